// Round 3
// baseline (253.558 us; speedup 1.0000x reference)
//
#include <hip/hip_runtime.h>
#include <math.h>

typedef __bf16 bf16x8 __attribute__((ext_vector_type(8)));
typedef __bf16 bf16x4 __attribute__((ext_vector_type(4)));
typedef float  floatx4 __attribute__((ext_vector_type(4)));
typedef float  floatx2 __attribute__((ext_vector_type(2)));

#define AS1(p) ((__attribute__((address_space(1))) void*)(p))
#define AS3(p) ((__attribute__((address_space(3))) void*)(p))

#define MASKV (-1.0e30f)
#define SOFTMAX_SCALE_LOG2 0.1803368801111244f   // 0.125 * log2(e)
#define ROPE_LOG2F 0.4152410118609203f           // log2(10000)/32

// raw barrier (no vmcnt drain, unlike __syncthreads) + compile-time sched fence
#define BARRIER do { __builtin_amdgcn_sched_barrier(0); \
                     __builtin_amdgcn_s_barrier(); \
                     __builtin_amdgcn_sched_barrier(0); } while (0)

// ---------------------------------------------------------------------------
// One-shot fp32 -> bf16 conversion of x/qkv/wo + rope cos/sin table build.
// ---------------------------------------------------------------------------
__global__ __launch_bounds__(256)
void cvt3_kernel(const float* __restrict__ x, const float* __restrict__ qkv,
                 const float* __restrict__ wo, __bf16* __restrict__ xb,
                 __bf16* __restrict__ qkvb, __bf16* __restrict__ wob,
                 float* __restrict__ rt)
{
    const int bi = blockIdx.x;
    if (bi >= 12288) {
        const int e0 = (bi - 12288) * 1024 + threadIdx.x * 4;
#pragma unroll
        for (int j = 0; j < 4; ++j) {
            const int e = e0 + j;
            const int s = e >> 5, d = e & 31;
            const float f = exp2f(-(float)d * ROPE_LOG2F);
            float sn, cs;
            sincosf((float)s * f, &sn, &cs);
            floatx2 t; t[0] = cs; t[1] = sn;
            *(floatx2*)(rt + e * 2) = t;
        }
        return;
    }
    const float* src;
    __bf16* dst;
    int base;
    if (bi < 8192)       { src = x;   dst = xb;   base = bi * 1024; }
    else if (bi < 11264) { src = qkv; dst = qkvb; base = (bi - 8192) * 1024; }
    else                 { src = wo;  dst = wob;  base = (bi - 11264) * 1024; }

    const int i = base + threadIdx.x * 4;
    const floatx4 v = *(const floatx4*)(src + i);
    bf16x4 o;
    o[0] = (__bf16)v[0]; o[1] = (__bf16)v[1];
    o[2] = (__bf16)v[2]; o[3] = (__bf16)v[3];
    *(bf16x4*)(dst + i) = o;
}

// ---------------------------------------------------------------------------
// Pipelined 128x256 GEMM core (C = A[128xK] * BT[256xK]^T tile), K=1024, BK=64.
// 8 waves (2M x 4N), 4-phase interleave, counted vmcnt, XOR-swizzled LDS.
// (unchanged from R1 — see R1 notes for the region/race ledger)
// ---------------------------------------------------------------------------
__device__ __forceinline__ void gemm_pipe(const __bf16* __restrict__ Ap,
                                          const __bf16* __restrict__ Bp,
                                          const int m0, const int n0,
                                          __bf16* smem, floatx4 (&acc)[4][4])
{
    const int tid  = threadIdx.x;
    const int wave = tid >> 6;
    const int lane = tid & 63;
    const int quad = lane >> 4;
    const int l16  = lane & 15;
    const int wr   = wave >> 2;
    const int wc   = wave & 3;

    const int arow = wr * 32 + l16;
    const int brow = (wc & 1) * 64 + l16;
    const int bsel = (wc >> 1) * 8192;
    const int swz  = (l16 & 7) << 4;
    int coff[2];
    coff[0] = (( (quad << 4))        ^ swz) >> 1;
    coff[1] = ((64 | (quad << 4))    ^ swz) >> 1;

    auto stageA = [&](int buf, int h, int k0) {
        const int o = tid << 4;
        const int r = o >> 7;
        const int c = (o & 127) ^ ((r & 7) << 4);
        const __bf16* src = Ap + (size_t)(m0 + h * 64 + r) * 1024 + k0 + (c >> 1);
        __builtin_amdgcn_global_load_lds(AS1(src),
            AS3(smem + buf * 24576 + h * 4096 + wave * 512), 16, 0, 0);
    };
    auto stageB = [&](int buf, int h, int k0) {
#pragma unroll
        for (int q = 0; q < 2; ++q) {
            const int o = (q * 512 + tid) << 4;
            const int r = o >> 7;
            const int c = (o & 127) ^ ((r & 7) << 4);
            const __bf16* src = Bp + (size_t)(n0 + h * 128 + r) * 1024 + k0 + (c >> 1);
            __builtin_amdgcn_global_load_lds(AS1(src),
                AS3(smem + buf * 24576 + 8192 + h * 8192 + (q * 8 + wave) * 512), 16, 0, 0);
        }
    };

#define RDA(P, qm, fm, ks) (*(const bf16x8*)(smem + (P) * 24576 + (qm) * 4096 \
                             + ((arow + (fm) * 16) << 6) + coff[ks]))
#define RDB(P, g, ks)      (*(const bf16x8*)(smem + (P) * 24576 + 8192 + bsel \
                             + ((brow + (g) * 16) << 6) + coff[ks]))
#define MFMA8(MB, NB, AV, BV) do { \
    _Pragma("unroll") for (int fm_ = 0; fm_ < 2; ++fm_) \
    _Pragma("unroll") for (int gi_ = 0; gi_ < 2; ++gi_) \
    _Pragma("unroll") for (int ks_ = 0; ks_ < 2; ++ks_) \
        acc[(MB) + fm_][(NB) + gi_] = __builtin_amdgcn_mfma_f32_16x16x32_bf16( \
            AV[fm_][ks_], BV[gi_][ks_], acc[(MB) + fm_][(NB) + gi_], 0, 0, 0); \
} while (0)

    stageA(0, 0, 0);  stageB(0, 0, 0);  stageA(0, 1, 0);  stageB(0, 1, 0);
    stageA(1, 0, 64); stageB(1, 0, 64); stageA(1, 1, 64);
    asm volatile("s_waitcnt vmcnt(4)" ::: "memory");
    BARRIER;

    bf16x8 a0[2][2], a1[2][2], b0[2][2], b1[2][2];

#define TILE(JT, P) do { \
    const int kn_ = ((JT) + 2) * 64; \
    _Pragma("unroll") for (int f_ = 0; f_ < 2; ++f_) \
    _Pragma("unroll") for (int k_ = 0; k_ < 2; ++k_) a0[f_][k_] = RDA(P, 0, f_, k_); \
    _Pragma("unroll") for (int g_ = 0; g_ < 2; ++g_) \
    _Pragma("unroll") for (int k_ = 0; k_ < 2; ++k_) b0[g_][k_] = RDB(P, g_, k_); \
    if ((JT) + 1 < 16) stageB(1 - (P), 1, ((JT) + 1) * 64); \
    BARRIER; \
    __builtin_amdgcn_s_setprio(1); MFMA8(0, 0, a0, b0); __builtin_amdgcn_s_setprio(0); \
    BARRIER; \
    _Pragma("unroll") for (int g_ = 0; g_ < 2; ++g_) \
    _Pragma("unroll") for (int k_ = 0; k_ < 2; ++k_) b1[g_][k_] = RDB(P, 2 + g_, k_); \
    if ((JT) + 2 < 16) stageA(P, 0, kn_); \
    BARRIER; \
    __builtin_amdgcn_s_setprio(1); MFMA8(0, 2, a0, b1); __builtin_amdgcn_s_setprio(0); \
    BARRIER; \
    _Pragma("unroll") for (int f_ = 0; f_ < 2; ++f_) \
    _Pragma("unroll") for (int k_ = 0; k_ < 2; ++k_) a1[f_][k_] = RDA(P, 1, f_, k_); \
    if ((JT) + 2 < 16) stageB(P, 0, kn_); \
    BARRIER; \
    __builtin_amdgcn_s_setprio(1); MFMA8(2, 2, a1, b1); __builtin_amdgcn_s_setprio(0); \
    BARRIER; \
    if ((JT) + 2 < 16) stageA(P, 1, kn_); \
    BARRIER; \
    __builtin_amdgcn_s_setprio(1); MFMA8(2, 0, a1, b0); __builtin_amdgcn_s_setprio(0); \
    if ((JT) + 2 < 16)      { asm volatile("s_waitcnt vmcnt(4)" ::: "memory"); } \
    else if ((JT) + 1 < 16) { asm volatile("s_waitcnt vmcnt(0)" ::: "memory"); } \
    BARRIER; \
} while (0)

    for (int it = 0; it < 8; ++it) {
        TILE(2 * it, 0);
        TILE(2 * it + 1, 1);
    }
#undef TILE
#undef RDA
#undef RDB
#undef MFMA8
}

// ---------------------------------------------------------------------------
// GEMM1 + fused RoPE + head-major scatter. Q pre-scaled by 0.125*log2e
// (applied on fp32 acc before the single bf16 rounding).
// ---------------------------------------------------------------------------
__global__ __launch_bounds__(512, 2)
void gemm_rope_kernel(const __bf16* __restrict__ A, const __bf16* __restrict__ BT,
                      __bf16* __restrict__ Qr, __bf16* __restrict__ Kr,
                      __bf16* __restrict__ Vt, const float* __restrict__ rt)
{
    extern __shared__ __align__(16) __bf16 smem[];
    const int id  = blockIdx.x;              // 768 = 64 m-tiles x 12 n-tiles
    const int xcd = id & 7, lid = id >> 3;
    const int tm  = xcd * 8 + lid / 12;
    const int tn  = lid % 12;
    const int m0  = tm * 128, n0 = tn * 256;

    floatx4 acc[4][4] = {};
    gemm_pipe(A, BT, m0, n0, smem, acc);

    const int tid  = threadIdx.x;
    const int wave = tid >> 6;
    const int lane = tid & 63;
    const int quad = lane >> 4, l16 = lane & 15;
    const int wr   = wave >> 2, wc = wave & 3;

    const int gn0    = n0 + wc * 64;
    const int region = gn0 >> 10;             // 0=Q, 1=K, 2=V
    const int h      = (gn0 >> 6) & 15;

    if (region == 2) {
#pragma unroll
        for (int f = 0; f < 4; ++f) {
            const int gm = m0 + (f >> 1) * 64 + wr * 32 + (f & 1) * 16 + quad * 4;
            const int b = gm >> 11, s = gm & 2047;
#pragma unroll
            for (int g = 0; g < 4; ++g) {
                const int d = g * 16 + l16;
                bf16x4 w;
#pragma unroll
                for (int r = 0; r < 4; ++r) w[r] = (__bf16)acc[f][g][r];
                *(bf16x4*)(Vt + ((size_t)(b * 16 + h) * 64 + d) * 2048 + s) = w;
            }
        }
    } else {
        __bf16* dst = region ? Kr : Qr;
        const float sc = region ? 1.0f : SOFTMAX_SCALE_LOG2;   // pre-scale Q
#pragma unroll
        for (int g = 0; g < 2; ++g) {
            const int d1 = g * 16 + l16;
#pragma unroll
            for (int f = 0; f < 4; ++f) {
                const int gm0 = m0 + (f >> 1) * 64 + wr * 32 + (f & 1) * 16 + quad * 4;
                const int b = gm0 >> 11, s0 = gm0 & 2047;
#pragma unroll
                for (int r = 0; r < 4; ++r) {
                    const floatx2 t = *(const floatx2*)(rt + ((s0 + r) * 32 + d1) * 2);
                    const float a1 = acc[f][g][r];
                    const float a2 = acc[f][g + 2][r];
                    __bf16* row = dst + ((size_t)((b * 16 + h) * 2048 + s0 + r)) * 64;
                    row[d1]      = (__bf16)((a1 * t[0] - a2 * t[1]) * sc);
                    row[d1 + 32] = (__bf16)((a2 * t[0] + a1 * t[1]) * sc);
                }
            }
        }
    }
}

// ---------------------------------------------------------------------------
// GEMM2: out[8192][1024] = ctx * wob^T, pipelined core (unchanged).
// ---------------------------------------------------------------------------
__global__ __launch_bounds__(512, 2)
void gemm_bt_kernel(const __bf16* __restrict__ A, const __bf16* __restrict__ BT,
                    float* __restrict__ C)
{
    extern __shared__ __align__(16) __bf16 smem[];
    const int id  = blockIdx.x;
    const int xcd = id & 7, lid = id >> 3;
    const int tm  = xcd * 8 + (lid >> 2);
    const int tn  = lid & 3;
    const int m0  = tm * 128, n0 = tn * 256;

    floatx4 acc[4][4] = {};
    gemm_pipe(A, BT, m0, n0, smem, acc);

    const int tid  = threadIdx.x;
    const int wave = tid >> 6, lane = tid & 63;
    const int quad = lane >> 4, l16 = lane & 15;
    const int wr   = wave >> 2, wc = wave & 3;

#pragma unroll
    for (int f = 0; f < 4; ++f) {
        const int row = m0 + (f >> 1) * 64 + wr * 32 + (f & 1) * 16 + quad * 4;
#pragma unroll
        for (int g = 0; g < 4; ++g) {
            const int col = n0 + wc * 64 + g * 16 + l16;
#pragma unroll
            for (int r = 0; r < 4; ++r)
                C[(size_t)(row + r) * 1024 + col] = acc[f][g][r];
        }
    }
}

// ---------------------------------------------------------------------------
// Causal flash attention v8 — 8-wave / 128-q-row blocks, single-buffered K/V
// (the proven R1 2-barrier tile structure; R2's double-buffer cost occupancy
// for zero gain). Per-tile fixed overhead (stage + vmcnt + 2 barriers) now
// amortized over 128 q-rows instead of 64; K/V HBM re-read halves.
// LDS = 8K (Ks) + 8K (Vs) + 18K (plds) = 34.8 KB -> 4 blocks/CU.
// Grid (64 bh, 8 tile-pairs {y, 15-y}) = 512 blocks x 34 iterations, uniform.
// Fully-masked waves (kt > q0+15) skip compute between barriers (wave-uniform
// branch; every thread still reaches both __syncthreads).
// ---------------------------------------------------------------------------
__global__ __launch_bounds__(512, 8)
void attn_kernel(const __bf16* __restrict__ Qr, const __bf16* __restrict__ Kr,
                 const __bf16* __restrict__ Vt, __bf16* __restrict__ ctx)
{
    __shared__ __align__(16) __bf16 Ks[64 * 64];        // [key][dh] swizzled
    __shared__ __align__(16) __bf16 Vs[64 * 64];        // [dh][key] swizzled
    __shared__ __align__(16) __bf16 plds[8][16 * 72];   // wave-private P staging

    const int bh   = blockIdx.x;
    const int b    = bh >> 4, h = bh & 15;
    const int tid  = threadIdx.x;            // 0..511
    const int wave = tid >> 6;               // 0..7
    const int lane = tid & 63;
    const int quad = lane >> 4, l16 = lane & 15;
    const int sw   = l16 & 7;                // read-side XOR swizzle

    const __bf16* Qb = Qr + (size_t)bh * 2048 * 64;
    const __bf16* Kb = Kr + (size_t)bh * 2048 * 64;
    const __bf16* Vb = Vt + (size_t)bh * 64 * 2048;
    __bf16* Pw = &plds[wave][0];

    // staging map: 512 threads x (1 K-load + 1 V-load), 16B each.
    // wave w writes LDS bytes [w*1024, w*1024+1024) = rows w*8..w*8+7; the
    // global source column jg implements the (row&7) XOR swizzle.
    const int row0 = tid >> 3;               // 0..63
    const int jg0  = (tid & 7) ^ (row0 & 7);

    const int tiles[2] = { (int)blockIdx.y, 15 - (int)blockIdx.y };

    for (int pass = 0; pass < 2; ++pass) {
        const int tq    = tiles[pass];
        const int q0b   = tq * 128;
        const int q0    = q0b + wave * 16;
        const int qa    = q0 + l16;
        const int ntile = 2 * tq + 2;        // 64-key tiles

        bf16x8 bq[2];
#pragma unroll
        for (int t = 0; t < 2; ++t)
            bq[t] = *(const bf16x8*)(Qb + (q0 + l16) * 64 + t * 32 + quad * 8);

        floatx4 o[4] = {};
        float lpart = 0.f;

        for (int t = 0; t < ntile; ++t) {
            const int kt = t * 64;
            __builtin_amdgcn_global_load_lds(AS1(Kb + (size_t)(kt + row0) * 64 + jg0 * 8),
                                             AS3(Ks + wave * 512), 16, 0, 0);
            __builtin_amdgcn_global_load_lds(AS1(Vb + (size_t)row0 * 2048 + kt + jg0 * 8),
                                             AS3(Vs + wave * 512), 16, 0, 0);
            asm volatile("s_waitcnt vmcnt(0)" ::: "memory");
            __syncthreads();

            if (kt <= q0 + 15) {             // wave-uniform: skip fully-masked
                const bool masked = (t >= ntile - 2);

                floatx4 s[4] = {};
                __builtin_amdgcn_s_setprio(1);
#pragma unroll
                for (int st = 0; st < 4; ++st) {
                    bf16x8 ka0 = *(const bf16x8*)(Ks + (st * 16 + l16) * 64 + ((0 + quad) ^ sw) * 8);
                    bf16x8 ka1 = *(const bf16x8*)(Ks + (st * 16 + l16) * 64 + ((4 + quad) ^ sw) * 8);
                    s[st] = __builtin_amdgcn_mfma_f32_16x16x32_bf16(ka0, bq[0], s[st], 0, 0, 0);
                    s[st] = __builtin_amdgcn_mfma_f32_16x16x32_bf16(ka1, bq[1], s[st], 0, 0, 0);
                }
                __builtin_amdgcn_s_setprio(0);

#pragma unroll
                for (int st = 0; st < 4; ++st) {
                    bf16x4 w;
#pragma unroll
                    for (int r = 0; r < 4; ++r) {
                        float v = s[st][r];
                        if (masked) {
                            const int key = kt + st * 16 + quad * 4 + r;
                            v = (key > qa) ? MASKV : v;
                        }
                        const float p = __builtin_amdgcn_exp2f(v);
                        lpart += p;
                        w[r] = (__bf16)p;
                    }
                    *(bf16x4*)(Pw + l16 * 72 + st * 16 + quad * 4) = w;
                }

                asm volatile("s_waitcnt lgkmcnt(0)" ::: "memory");
                bf16x8 ap0 = *(const bf16x8*)(Pw + l16 * 72 + quad * 8);
                bf16x8 ap1 = *(const bf16x8*)(Pw + l16 * 72 + 32 + quad * 8);

                __builtin_amdgcn_s_setprio(1);
#pragma unroll
                for (int nt = 0; nt < 4; ++nt) {
                    bf16x8 bv0 = *(const bf16x8*)(Vs + (nt * 16 + l16) * 64 + ((0 + quad) ^ sw) * 8);
                    bf16x8 bv1 = *(const bf16x8*)(Vs + (nt * 16 + l16) * 64 + ((4 + quad) ^ sw) * 8);
                    o[nt] = __builtin_amdgcn_mfma_f32_16x16x32_bf16(ap0, bv0, o[nt], 0, 0, 0);
                    o[nt] = __builtin_amdgcn_mfma_f32_16x16x32_bf16(ap1, bv1, o[nt], 0, 0, 0);
                }
                __builtin_amdgcn_s_setprio(0);
            }

            __syncthreads();
        }

        float l = lpart;
        l += __shfl_xor(l, 16, 64);
        l += __shfl_xor(l, 32, 64);
        float lr[4];
#pragma unroll
        for (int r = 0; r < 4; ++r)
            lr[r] = __shfl(l, quad * 4 + r, 64);
#pragma unroll
        for (int nt = 0; nt < 4; ++nt)
#pragma unroll
            for (int r = 0; r < 4; ++r) {
                const int srow = q0 + quad * 4 + r;
                const float inv_l = 1.0f / fmaxf(lr[r], 1e-20f);
                ctx[((size_t)(b * 2048 + srow)) * 1024 + h * 64 + nt * 16 + l16] =
                    (__bf16)(o[nt][r] * inv_l);
            }
    }
}

// ---------------------------------------------------------------------------
// Workspace layout (88.5 MiB):
//   xb   [ 0M..16M)   qkvb [16M..22M)   wob [22M..24M)
//   Qr   [24M..40M)   Kr   [40M..56M)   Vt  [56M..72M)   ctx [72M..88M)
//   rt   [88M..88.5M) rope cos/sin table (2048 x 32 float2)
// ---------------------------------------------------------------------------
extern "C" void kernel_launch(void* const* d_in, const int* in_sizes, int n_in,
                              void* d_out, int out_size, void* d_ws, size_t ws_size,
                              hipStream_t stream)
{
    const float* x   = (const float*)d_in[0];   // [4,2048,1024] fp32
    const float* qkv = (const float*)d_in[1];   // [3072,1024]   fp32 (N x K)
    const float* wo  = (const float*)d_in[2];   // [1024,1024]   fp32 (N x K)
    float* out = (float*)d_out;                 // [8192,1024]   fp32

    char* ws = (char*)d_ws;
    const size_t MB = 1024 * 1024;
    __bf16* xb   = (__bf16*)(ws);
    __bf16* qkvb = (__bf16*)(ws + 16 * MB);
    __bf16* wob  = (__bf16*)(ws + 22 * MB);
    __bf16* Qr   = (__bf16*)(ws + 24 * MB);
    __bf16* Kr   = (__bf16*)(ws + 40 * MB);
    __bf16* Vt   = (__bf16*)(ws + 56 * MB);
    __bf16* ctx  = (__bf16*)(ws + 72 * MB);
    float*  rt   = (float*) (ws + 88 * MB);

    hipFuncSetAttribute((const void*)gemm_rope_kernel,
                        hipFuncAttributeMaxDynamicSharedMemorySize, 98304);
    hipFuncSetAttribute((const void*)gemm_bt_kernel,
                        hipFuncAttributeMaxDynamicSharedMemorySize, 98304);

    // 0) conversions + rope table in one launch
    cvt3_kernel<<<12352, 256, 0, stream>>>(x, qkv, wo, xb, qkvb, wob, rt);
    // 1) QKV projection, pipelined, fused table-RoPE (+Q pre-scale)
    gemm_rope_kernel<<<768, 512, 98304, stream>>>(xb, qkvb, Qr, Kr, Vt, rt);
    // 2) causal flash attention (8-wave / 128-row blocks) -> ctx (bf16)
    attn_kernel<<<dim3(64, 8), 512, 0, stream>>>(Qr, Kr, Vt, ctx);
    // 3) output projection, pipelined -> fp32 out
    gemm_bt_kernel<<<256, 512, 98304, stream>>>(ctx, wob, out);
}

// Round 4
// 237.659 us; speedup vs baseline: 1.0669x; 1.0669x over previous
//
#include <hip/hip_runtime.h>
#include <math.h>

typedef __bf16 bf16x8 __attribute__((ext_vector_type(8)));
typedef __bf16 bf16x4 __attribute__((ext_vector_type(4)));
typedef float  floatx4 __attribute__((ext_vector_type(4)));
typedef float  floatx2 __attribute__((ext_vector_type(2)));

#define AS1(p) ((__attribute__((address_space(1))) void*)(p))
#define AS3(p) ((__attribute__((address_space(3))) void*)(p))

#define MASKV (-1.0e30f)
#define SOFTMAX_SCALE_LOG2 0.1803368801111244f   // 0.125 * log2(e)
#define ROPE_LOG2F 0.4152410118609203f           // log2(10000)/32

// raw barrier (no vmcnt drain, unlike __syncthreads) + compile-time sched fence
#define BARRIER do { __builtin_amdgcn_sched_barrier(0); \
                     __builtin_amdgcn_s_barrier(); \
                     __builtin_amdgcn_sched_barrier(0); } while (0)

// ---------------------------------------------------------------------------
// One-shot fp32 -> bf16 conversion of x/qkv/wo + rope cos/sin table build.
// ---------------------------------------------------------------------------
__global__ __launch_bounds__(256)
void cvt3_kernel(const float* __restrict__ x, const float* __restrict__ qkv,
                 const float* __restrict__ wo, __bf16* __restrict__ xb,
                 __bf16* __restrict__ qkvb, __bf16* __restrict__ wob,
                 float* __restrict__ rt)
{
    const int bi = blockIdx.x;
    if (bi >= 12288) {
        const int e0 = (bi - 12288) * 1024 + threadIdx.x * 4;
#pragma unroll
        for (int j = 0; j < 4; ++j) {
            const int e = e0 + j;
            const int s = e >> 5, d = e & 31;
            const float f = exp2f(-(float)d * ROPE_LOG2F);
            float sn, cs;
            sincosf((float)s * f, &sn, &cs);
            floatx2 t; t[0] = cs; t[1] = sn;
            *(floatx2*)(rt + e * 2) = t;
        }
        return;
    }
    const float* src;
    __bf16* dst;
    int base;
    if (bi < 8192)       { src = x;   dst = xb;   base = bi * 1024; }
    else if (bi < 11264) { src = qkv; dst = qkvb; base = (bi - 8192) * 1024; }
    else                 { src = wo;  dst = wob;  base = (bi - 11264) * 1024; }

    const int i = base + threadIdx.x * 4;
    const floatx4 v = *(const floatx4*)(src + i);
    bf16x4 o;
    o[0] = (__bf16)v[0]; o[1] = (__bf16)v[1];
    o[2] = (__bf16)v[2]; o[3] = (__bf16)v[3];
    *(bf16x4*)(dst + i) = o;
}

// ---------------------------------------------------------------------------
// Pipelined 128x256 GEMM core (C = A[128xK] * BT[256xK]^T tile), K=1024, BK=64.
// 8 waves (2M x 4N), 4-phase interleave, counted vmcnt, XOR-swizzled LDS.
// (unchanged from R1 — see R1 notes for the region/race ledger)
// ---------------------------------------------------------------------------
__device__ __forceinline__ void gemm_pipe(const __bf16* __restrict__ Ap,
                                          const __bf16* __restrict__ Bp,
                                          const int m0, const int n0,
                                          __bf16* smem, floatx4 (&acc)[4][4])
{
    const int tid  = threadIdx.x;
    const int wave = tid >> 6;
    const int lane = tid & 63;
    const int quad = lane >> 4;
    const int l16  = lane & 15;
    const int wr   = wave >> 2;
    const int wc   = wave & 3;

    const int arow = wr * 32 + l16;
    const int brow = (wc & 1) * 64 + l16;
    const int bsel = (wc >> 1) * 8192;
    const int swz  = (l16 & 7) << 4;
    int coff[2];
    coff[0] = (( (quad << 4))        ^ swz) >> 1;
    coff[1] = ((64 | (quad << 4))    ^ swz) >> 1;

    auto stageA = [&](int buf, int h, int k0) {
        const int o = tid << 4;
        const int r = o >> 7;
        const int c = (o & 127) ^ ((r & 7) << 4);
        const __bf16* src = Ap + (size_t)(m0 + h * 64 + r) * 1024 + k0 + (c >> 1);
        __builtin_amdgcn_global_load_lds(AS1(src),
            AS3(smem + buf * 24576 + h * 4096 + wave * 512), 16, 0, 0);
    };
    auto stageB = [&](int buf, int h, int k0) {
#pragma unroll
        for (int q = 0; q < 2; ++q) {
            const int o = (q * 512 + tid) << 4;
            const int r = o >> 7;
            const int c = (o & 127) ^ ((r & 7) << 4);
            const __bf16* src = Bp + (size_t)(n0 + h * 128 + r) * 1024 + k0 + (c >> 1);
            __builtin_amdgcn_global_load_lds(AS1(src),
                AS3(smem + buf * 24576 + 8192 + h * 8192 + (q * 8 + wave) * 512), 16, 0, 0);
        }
    };

#define RDA(P, qm, fm, ks) (*(const bf16x8*)(smem + (P) * 24576 + (qm) * 4096 \
                             + ((arow + (fm) * 16) << 6) + coff[ks]))
#define RDB(P, g, ks)      (*(const bf16x8*)(smem + (P) * 24576 + 8192 + bsel \
                             + ((brow + (g) * 16) << 6) + coff[ks]))
#define MFMA8(MB, NB, AV, BV) do { \
    _Pragma("unroll") for (int fm_ = 0; fm_ < 2; ++fm_) \
    _Pragma("unroll") for (int gi_ = 0; gi_ < 2; ++gi_) \
    _Pragma("unroll") for (int ks_ = 0; ks_ < 2; ++ks_) \
        acc[(MB) + fm_][(NB) + gi_] = __builtin_amdgcn_mfma_f32_16x16x32_bf16( \
            AV[fm_][ks_], BV[gi_][ks_], acc[(MB) + fm_][(NB) + gi_], 0, 0, 0); \
} while (0)

    stageA(0, 0, 0);  stageB(0, 0, 0);  stageA(0, 1, 0);  stageB(0, 1, 0);
    stageA(1, 0, 64); stageB(1, 0, 64); stageA(1, 1, 64);
    asm volatile("s_waitcnt vmcnt(4)" ::: "memory");
    BARRIER;

    bf16x8 a0[2][2], a1[2][2], b0[2][2], b1[2][2];

#define TILE(JT, P) do { \
    const int kn_ = ((JT) + 2) * 64; \
    _Pragma("unroll") for (int f_ = 0; f_ < 2; ++f_) \
    _Pragma("unroll") for (int k_ = 0; k_ < 2; ++k_) a0[f_][k_] = RDA(P, 0, f_, k_); \
    _Pragma("unroll") for (int g_ = 0; g_ < 2; ++g_) \
    _Pragma("unroll") for (int k_ = 0; k_ < 2; ++k_) b0[g_][k_] = RDB(P, g_, k_); \
    if ((JT) + 1 < 16) stageB(1 - (P), 1, ((JT) + 1) * 64); \
    BARRIER; \
    __builtin_amdgcn_s_setprio(1); MFMA8(0, 0, a0, b0); __builtin_amdgcn_s_setprio(0); \
    BARRIER; \
    _Pragma("unroll") for (int g_ = 0; g_ < 2; ++g_) \
    _Pragma("unroll") for (int k_ = 0; k_ < 2; ++k_) b1[g_][k_] = RDB(P, 2 + g_, k_); \
    if ((JT) + 2 < 16) stageA(P, 0, kn_); \
    BARRIER; \
    __builtin_amdgcn_s_setprio(1); MFMA8(0, 2, a0, b1); __builtin_amdgcn_s_setprio(0); \
    BARRIER; \
    _Pragma("unroll") for (int f_ = 0; f_ < 2; ++f_) \
    _Pragma("unroll") for (int k_ = 0; k_ < 2; ++k_) a1[f_][k_] = RDA(P, 1, f_, k_); \
    if ((JT) + 2 < 16) stageB(P, 0, kn_); \
    BARRIER; \
    __builtin_amdgcn_s_setprio(1); MFMA8(2, 2, a1, b1); __builtin_amdgcn_s_setprio(0); \
    BARRIER; \
    if ((JT) + 2 < 16) stageA(P, 1, kn_); \
    BARRIER; \
    __builtin_amdgcn_s_setprio(1); MFMA8(2, 0, a1, b0); __builtin_amdgcn_s_setprio(0); \
    if ((JT) + 2 < 16)      { asm volatile("s_waitcnt vmcnt(4)" ::: "memory"); } \
    else if ((JT) + 1 < 16) { asm volatile("s_waitcnt vmcnt(0)" ::: "memory"); } \
    BARRIER; \
} while (0)

    for (int it = 0; it < 8; ++it) {
        TILE(2 * it, 0);
        TILE(2 * it + 1, 1);
    }
#undef TILE
#undef RDA
#undef RDB
#undef MFMA8
}

// ---------------------------------------------------------------------------
// GEMM1 + fused RoPE + head-major scatter. Q pre-scaled by 0.125*log2e
// (applied on fp32 acc before the single bf16 rounding).
// ---------------------------------------------------------------------------
__global__ __launch_bounds__(512, 2)
void gemm_rope_kernel(const __bf16* __restrict__ A, const __bf16* __restrict__ BT,
                      __bf16* __restrict__ Qr, __bf16* __restrict__ Kr,
                      __bf16* __restrict__ Vt, const float* __restrict__ rt)
{
    extern __shared__ __align__(16) __bf16 smem[];
    const int id  = blockIdx.x;              // 768 = 64 m-tiles x 12 n-tiles
    const int xcd = id & 7, lid = id >> 3;
    const int tm  = xcd * 8 + lid / 12;
    const int tn  = lid % 12;
    const int m0  = tm * 128, n0 = tn * 256;

    floatx4 acc[4][4] = {};
    gemm_pipe(A, BT, m0, n0, smem, acc);

    const int tid  = threadIdx.x;
    const int wave = tid >> 6;
    const int lane = tid & 63;
    const int quad = lane >> 4, l16 = lane & 15;
    const int wr   = wave >> 2, wc = wave & 3;

    const int gn0    = n0 + wc * 64;
    const int region = gn0 >> 10;             // 0=Q, 1=K, 2=V
    const int h      = (gn0 >> 6) & 15;

    if (region == 2) {
#pragma unroll
        for (int f = 0; f < 4; ++f) {
            const int gm = m0 + (f >> 1) * 64 + wr * 32 + (f & 1) * 16 + quad * 4;
            const int b = gm >> 11, s = gm & 2047;
#pragma unroll
            for (int g = 0; g < 4; ++g) {
                const int d = g * 16 + l16;
                bf16x4 w;
#pragma unroll
                for (int r = 0; r < 4; ++r) w[r] = (__bf16)acc[f][g][r];
                *(bf16x4*)(Vt + ((size_t)(b * 16 + h) * 64 + d) * 2048 + s) = w;
            }
        }
    } else {
        __bf16* dst = region ? Kr : Qr;
        const float sc = region ? 1.0f : SOFTMAX_SCALE_LOG2;   // pre-scale Q
#pragma unroll
        for (int g = 0; g < 2; ++g) {
            const int d1 = g * 16 + l16;
#pragma unroll
            for (int f = 0; f < 4; ++f) {
                const int gm0 = m0 + (f >> 1) * 64 + wr * 32 + (f & 1) * 16 + quad * 4;
                const int b = gm0 >> 11, s0 = gm0 & 2047;
#pragma unroll
                for (int r = 0; r < 4; ++r) {
                    const floatx2 t = *(const floatx2*)(rt + ((s0 + r) * 32 + d1) * 2);
                    const float a1 = acc[f][g][r];
                    const float a2 = acc[f][g + 2][r];
                    __bf16* row = dst + ((size_t)((b * 16 + h) * 2048 + s0 + r)) * 64;
                    row[d1]      = (__bf16)((a1 * t[0] - a2 * t[1]) * sc);
                    row[d1 + 32] = (__bf16)((a2 * t[0] + a1 * t[1]) * sc);
                }
            }
        }
    }
}

// ---------------------------------------------------------------------------
// GEMM2: out[8192][1024] = ctx * wob^T, pipelined core (unchanged).
// ---------------------------------------------------------------------------
__global__ __launch_bounds__(512, 2)
void gemm_bt_kernel(const __bf16* __restrict__ A, const __bf16* __restrict__ BT,
                    float* __restrict__ C)
{
    extern __shared__ __align__(16) __bf16 smem[];
    const int id  = blockIdx.x;
    const int xcd = id & 7, lid = id >> 3;
    const int tm  = xcd * 8 + (lid >> 2);
    const int tn  = lid & 3;
    const int m0  = tm * 128, n0 = tn * 256;

    floatx4 acc[4][4] = {};
    gemm_pipe(A, BT, m0, n0, smem, acc);

    const int tid  = threadIdx.x;
    const int wave = tid >> 6, lane = tid & 63;
    const int quad = lane >> 4, l16 = lane & 15;
    const int wr   = wave >> 2, wc = wave & 3;

#pragma unroll
    for (int f = 0; f < 4; ++f) {
        const int row = m0 + (f >> 1) * 64 + wr * 32 + (f & 1) * 16 + quad * 4;
#pragma unroll
        for (int g = 0; g < 4; ++g) {
            const int col = n0 + wc * 64 + g * 16 + l16;
#pragma unroll
            for (int r = 0; r < 4; ++r)
                C[(size_t)(row + r) * 1024 + col] = acc[f][g][r];
        }
    }
}

// ---------------------------------------------------------------------------
// Causal flash attention v9 — R1 geometry (4 waves / 64 q-rows, 1024 blocks,
// 25.6 KB LDS) + T14 async-STAGE split: tile t+1's K/V loaded to REGISTERS
// during tile t's compute, written to LDS at tile t+1's head. The per-tile
// vmcnt(0) now waits loads issued a full tile (~1500 cy) earlier -> HBM/L2
// latency hidden. LDS image (incl. XOR swizzle) is byte-identical to R1's
// global_load_lds version; only the transport changed.
// Race ledger: reg loads wave-private; ds_write(t+1) happens after tile t's
// end BARRIER (all waves' LDS reads consumed into MFMAs via data-dep lgkm
// waits before that barrier); lgkmcnt(0) precedes the post-write BARRIER so
// writes are visible; __syncthreads at pass start protects cross-pass reuse.
// Also: Q pre-scaled at projection; mask applied only on the diagonal tile
// (t == ntile-1); setprio(1) around both MFMA clusters.
// ---------------------------------------------------------------------------
__global__ __launch_bounds__(256, 4)
void attn_kernel(const __bf16* __restrict__ Qr, const __bf16* __restrict__ Kr,
                 const __bf16* __restrict__ Vt, __bf16* __restrict__ ctx)
{
    __shared__ __align__(16) __bf16 Ks[64 * 64];        // [key][dh] swizzled
    __shared__ __align__(16) __bf16 Vs[64 * 64];        // [dh][key] swizzled
    __shared__ __align__(16) __bf16 plds[4][16 * 72];   // wave-private P staging

    const int bh   = blockIdx.x;
    const int b    = bh >> 4, h = bh & 15;
    const int tid  = threadIdx.x;
    const int wave = tid >> 6;
    const int lane = tid & 63;
    const int quad = lane >> 4, l16 = lane & 15;
    const int sw   = l16 & 7;                 // read-side XOR swizzle

    const __bf16* Qb = Qr + (size_t)bh * 2048 * 64;
    const __bf16* Kb = Kr + (size_t)bh * 2048 * 64;
    const __bf16* Vb = Vt + (size_t)bh * 64 * 2048;
    __bf16* Pw = &plds[wave][0];

    // staging map (identical LDS image to global_load_lds version):
    // chunk0: LDS bytes tid*16        <- K row0 = tid>>3,      col jg0 (swz)
    // chunk1: LDS bytes 4096 + tid*16 <- K row1 = 32+(tid>>3), col jg1 (swz)
    const int row0 = tid >> 3, jg0 = (tid & 7) ^ (row0 & 7);
    const int c1   = 256 + tid;
    const int row1 = c1 >> 3, jg1 = (c1 & 7) ^ (row1 & 7);

    const __bf16* pK0 = Kb + (size_t)row0 * 64 + jg0 * 8;
    const __bf16* pK1 = Kb + (size_t)row1 * 64 + jg1 * 8;
    const __bf16* pV0 = Vb + (size_t)row0 * 2048 + jg0 * 8;
    const __bf16* pV1 = Vb + (size_t)row1 * 2048 + jg1 * 8;

    const int tiles[2] = { (int)blockIdx.y, 31 - (int)blockIdx.y };

    for (int pass = 0; pass < 2; ++pass) {
        const int tq    = tiles[pass];
        const int q0    = tq * 64 + wave * 16;
        const int qa    = q0 + l16;
        const int ntile = tq + 1;

        bf16x8 bq[2];
#pragma unroll
        for (int t = 0; t < 2; ++t)
            bq[t] = *(const bf16x8*)(Qb + (q0 + l16) * 64 + t * 32 + quad * 8);

        floatx4 o[4] = {};
        float lpart = 0.f;

        // prologue: tile-0 K/V into registers
        bf16x8 rk0 = *(const bf16x8*)pK0;
        bf16x8 rk1 = *(const bf16x8*)pK1;
        bf16x8 rv0 = *(const bf16x8*)pV0;
        bf16x8 rv1 = *(const bf16x8*)pV1;

        __syncthreads();     // all waves done reading Ks/Vs of previous pass

        for (int t = 0; t < ntile; ++t) {
            // ---- write phase: regs (tile t) -> LDS
            asm volatile("s_waitcnt vmcnt(0)" ::: "memory");
            *(bf16x8*)(Ks + tid * 8)        = rk0;
            *(bf16x8*)(Ks + 2048 + tid * 8) = rk1;
            *(bf16x8*)(Vs + tid * 8)        = rv0;
            *(bf16x8*)(Vs + 2048 + tid * 8) = rv1;
            asm volatile("s_waitcnt lgkmcnt(0)" ::: "memory");
            BARRIER;

            // ---- issue next tile's loads (overlap with all compute below)
            if (t + 1 < ntile) {
                rk0 = *(const bf16x8*)(pK0 + (size_t)(t + 1) * 4096);
                rk1 = *(const bf16x8*)(pK1 + (size_t)(t + 1) * 4096);
                rv0 = *(const bf16x8*)(pV0 + (t + 1) * 64);
                rv1 = *(const bf16x8*)(pV1 + (t + 1) * 64);
            }

            const int  kt     = t * 64;
            const bool masked = (t == ntile - 1);   // only diag tile crosses q

            // ---- QK^T
            floatx4 s[4] = {};
            __builtin_amdgcn_s_setprio(1);
#pragma unroll
            for (int st = 0; st < 4; ++st) {
                bf16x8 ka0 = *(const bf16x8*)(Ks + (st * 16 + l16) * 64 + ((0 + quad) ^ sw) * 8);
                bf16x8 ka1 = *(const bf16x8*)(Ks + (st * 16 + l16) * 64 + ((4 + quad) ^ sw) * 8);
                s[st] = __builtin_amdgcn_mfma_f32_16x16x32_bf16(ka0, bq[0], s[st], 0, 0, 0);
                s[st] = __builtin_amdgcn_mfma_f32_16x16x32_bf16(ka1, bq[1], s[st], 0, 0, 0);
            }
            __builtin_amdgcn_s_setprio(0);

            // ---- softmax (Q pre-scaled; exp2 direct)
#pragma unroll
            for (int st = 0; st < 4; ++st) {
                bf16x4 w;
#pragma unroll
                for (int r = 0; r < 4; ++r) {
                    float v = s[st][r];
                    if (masked) {
                        const int key = kt + st * 16 + quad * 4 + r;
                        v = (key > qa) ? MASKV : v;
                    }
                    const float p = __builtin_amdgcn_exp2f(v);
                    lpart += p;
                    w[r] = (__bf16)p;
                }
                *(bf16x4*)(Pw + l16 * 72 + st * 16 + quad * 4) = w;
            }

            asm volatile("s_waitcnt lgkmcnt(0)" ::: "memory");
            bf16x8 ap0 = *(const bf16x8*)(Pw + l16 * 72 + quad * 8);
            bf16x8 ap1 = *(const bf16x8*)(Pw + l16 * 72 + 32 + quad * 8);

            // ---- PV
            __builtin_amdgcn_s_setprio(1);
#pragma unroll
            for (int nt = 0; nt < 4; ++nt) {
                bf16x8 bv0 = *(const bf16x8*)(Vs + (nt * 16 + l16) * 64 + ((0 + quad) ^ sw) * 8);
                bf16x8 bv1 = *(const bf16x8*)(Vs + (nt * 16 + l16) * 64 + ((4 + quad) ^ sw) * 8);
                o[nt] = __builtin_amdgcn_mfma_f32_16x16x32_bf16(ap0, bv0, o[nt], 0, 0, 0);
                o[nt] = __builtin_amdgcn_mfma_f32_16x16x32_bf16(ap1, bv1, o[nt], 0, 0, 0);
            }
            __builtin_amdgcn_s_setprio(0);

            BARRIER;          // all waves' reads of tile t done -> next write
        }

        float l = lpart;
        l += __shfl_xor(l, 16, 64);
        l += __shfl_xor(l, 32, 64);
        float lr[4];
#pragma unroll
        for (int r = 0; r < 4; ++r)
            lr[r] = __shfl(l, quad * 4 + r, 64);
#pragma unroll
        for (int nt = 0; nt < 4; ++nt)
#pragma unroll
            for (int r = 0; r < 4; ++r) {
                const int srow = q0 + quad * 4 + r;
                const float inv_l = 1.0f / fmaxf(lr[r], 1e-20f);
                ctx[((size_t)(b * 2048 + srow)) * 1024 + h * 64 + nt * 16 + l16] =
                    (__bf16)(o[nt][r] * inv_l);
            }
    }
}

// ---------------------------------------------------------------------------
// Workspace layout (88.5 MiB):
//   xb   [ 0M..16M)   qkvb [16M..22M)   wob [22M..24M)
//   Qr   [24M..40M)   Kr   [40M..56M)   Vt  [56M..72M)   ctx [72M..88M)
//   rt   [88M..88.5M) rope cos/sin table (2048 x 32 float2)
// ---------------------------------------------------------------------------
extern "C" void kernel_launch(void* const* d_in, const int* in_sizes, int n_in,
                              void* d_out, int out_size, void* d_ws, size_t ws_size,
                              hipStream_t stream)
{
    const float* x   = (const float*)d_in[0];   // [4,2048,1024] fp32
    const float* qkv = (const float*)d_in[1];   // [3072,1024]   fp32 (N x K)
    const float* wo  = (const float*)d_in[2];   // [1024,1024]   fp32 (N x K)
    float* out = (float*)d_out;                 // [8192,1024]   fp32

    char* ws = (char*)d_ws;
    const size_t MB = 1024 * 1024;
    __bf16* xb   = (__bf16*)(ws);
    __bf16* qkvb = (__bf16*)(ws + 16 * MB);
    __bf16* wob  = (__bf16*)(ws + 22 * MB);
    __bf16* Qr   = (__bf16*)(ws + 24 * MB);
    __bf16* Kr   = (__bf16*)(ws + 40 * MB);
    __bf16* Vt   = (__bf16*)(ws + 56 * MB);
    __bf16* ctx  = (__bf16*)(ws + 72 * MB);
    float*  rt   = (float*) (ws + 88 * MB);

    hipFuncSetAttribute((const void*)gemm_rope_kernel,
                        hipFuncAttributeMaxDynamicSharedMemorySize, 98304);
    hipFuncSetAttribute((const void*)gemm_bt_kernel,
                        hipFuncAttributeMaxDynamicSharedMemorySize, 98304);

    // 0) conversions + rope table in one launch
    cvt3_kernel<<<12352, 256, 0, stream>>>(x, qkv, wo, xb, qkvb, wob, rt);
    // 1) QKV projection, pipelined, fused table-RoPE (+Q pre-scale)
    gemm_rope_kernel<<<768, 512, 98304, stream>>>(xb, qkvb, Qr, Kr, Vt, rt);
    // 2) causal flash attention (T14 reg-staged) -> ctx (bf16)
    attn_kernel<<<dim3(64, 16), 256, 0, stream>>>(Qr, Kr, Vt, ctx);
    // 3) output projection, pipelined -> fp32 out
    gemm_bt_kernel<<<256, 512, 98304, stream>>>(ctx, wob, out);
}

// Round 5
// 225.172 us; speedup vs baseline: 1.1261x; 1.0555x over previous
//
#include <hip/hip_runtime.h>
#include <math.h>

typedef __bf16 bf16x8 __attribute__((ext_vector_type(8)));
typedef __bf16 bf16x4 __attribute__((ext_vector_type(4)));
typedef float  floatx4 __attribute__((ext_vector_type(4)));
typedef float  floatx2 __attribute__((ext_vector_type(2)));

#define AS1(p) ((__attribute__((address_space(1))) void*)(p))
#define AS3(p) ((__attribute__((address_space(3))) void*)(p))

#define MASKV (-1.0e30f)
#define SOFTMAX_SCALE_LOG2 0.1803368801111244f   // 0.125 * log2(e)
#define ROPE_LOG2F 0.4152410118609203f           // log2(10000)/32

// raw barrier (no vmcnt drain, unlike __syncthreads) + compile-time sched fence
#define BARRIER do { __builtin_amdgcn_sched_barrier(0); \
                     __builtin_amdgcn_s_barrier(); \
                     __builtin_amdgcn_sched_barrier(0); } while (0)

// ---------------------------------------------------------------------------
// One-shot fp32 -> bf16 conversion of x/qkv/wo + rope cos/sin table build.
// ---------------------------------------------------------------------------
__global__ __launch_bounds__(256)
void cvt3_kernel(const float* __restrict__ x, const float* __restrict__ qkv,
                 const float* __restrict__ wo, __bf16* __restrict__ xb,
                 __bf16* __restrict__ qkvb, __bf16* __restrict__ wob,
                 float* __restrict__ rt)
{
    const int bi = blockIdx.x;
    if (bi >= 12288) {
        const int e0 = (bi - 12288) * 1024 + threadIdx.x * 4;
#pragma unroll
        for (int j = 0; j < 4; ++j) {
            const int e = e0 + j;
            const int s = e >> 5, d = e & 31;
            const float f = exp2f(-(float)d * ROPE_LOG2F);
            float sn, cs;
            sincosf((float)s * f, &sn, &cs);
            floatx2 t; t[0] = cs; t[1] = sn;
            *(floatx2*)(rt + e * 2) = t;
        }
        return;
    }
    const float* src;
    __bf16* dst;
    int base;
    if (bi < 8192)       { src = x;   dst = xb;   base = bi * 1024; }
    else if (bi < 11264) { src = qkv; dst = qkvb; base = (bi - 8192) * 1024; }
    else                 { src = wo;  dst = wob;  base = (bi - 11264) * 1024; }

    const int i = base + threadIdx.x * 4;
    const floatx4 v = *(const floatx4*)(src + i);
    bf16x4 o;
    o[0] = (__bf16)v[0]; o[1] = (__bf16)v[1];
    o[2] = (__bf16)v[2]; o[3] = (__bf16)v[3];
    *(bf16x4*)(dst + i) = o;
}

// ---------------------------------------------------------------------------
// Pipelined 128x256 GEMM core v2 (C = A[128xK] * BT[256xK]^T tile), K=1024,
// BK=64, 8 waves (2M x 4N). 2 phases per K-tile, 16 MFMA per barrier-pair
// (m201 parity; v1 had 8 -> barrier-density-bound at MfmaUtil 31%).
//   ph1: stage A1(j+1)->other buf; read a0-half + ALL b (12 ds_read_b128);
//        bar; 16 MFMA (acc rows 0-1); bar.
//   ph2: stage A0(j+2)+B(j+2)->this buf (5 loads); read a1-half (4);
//        bar; 16 MFMA (acc rows 2-3); vmcnt(5); bar.
// Region ledger: A1(j+1)->buf(1-P).A1 last read ph2(j-1) [closed];
// A0/B(j+2)->bufP last read ph1(j) [closed]. Issue-order ledger at the
// end-of-tile wait: outstanding = {A0,B}(j+2) = 5 newest; everything older
// (incl. A1(j+1) issued ph1(j)) completes -> vmcnt(5), never 0 mid-loop.
// LDS: 2 bufs x 48 KB {A0 @0, A1 @4096, B0 @8192, B1 @16384 elems},
// XOR swizzle byte^=(row&7)<<4, inverse-swizzled global source (rule 21).
// ---------------------------------------------------------------------------
__device__ __forceinline__ void gemm_pipe(const __bf16* __restrict__ Ap,
                                          const __bf16* __restrict__ Bp,
                                          const int m0, const int n0,
                                          __bf16* smem, floatx4 (&acc)[4][4])
{
    const int tid  = threadIdx.x;
    const int wave = tid >> 6;
    const int lane = tid & 63;
    const int quad = lane >> 4;
    const int l16  = lane & 15;
    const int wr   = wave >> 2;
    const int wc   = wave & 3;

    const int arow = wr * 32 + l16;
    const int brow = (wc & 1) * 64 + l16;
    const int bsel = (wc >> 1) * 8192;
    const int swz  = (l16 & 7) << 4;
    int coff[2];
    coff[0] = (( (quad << 4))        ^ swz) >> 1;
    coff[1] = ((64 | (quad << 4))    ^ swz) >> 1;

    auto stageA = [&](int buf, int h, int k0) {          // 1 load/thread (8KB)
        const int o = tid << 4;
        const int r = o >> 7;
        const int c = (o & 127) ^ ((r & 7) << 4);
        const __bf16* src = Ap + (size_t)(m0 + h * 64 + r) * 1024 + k0 + (c >> 1);
        __builtin_amdgcn_global_load_lds(AS1(src),
            AS3(smem + buf * 24576 + h * 4096 + wave * 512), 16, 0, 0);
    };
    auto stageB = [&](int buf, int h, int k0) {          // 2 loads/thread (16KB)
#pragma unroll
        for (int q = 0; q < 2; ++q) {
            const int o = (q * 512 + tid) << 4;
            const int r = o >> 7;
            const int c = (o & 127) ^ ((r & 7) << 4);
            const __bf16* src = Bp + (size_t)(n0 + h * 128 + r) * 1024 + k0 + (c >> 1);
            __builtin_amdgcn_global_load_lds(AS1(src),
                AS3(smem + buf * 24576 + 8192 + h * 8192 + (q * 8 + wave) * 512), 16, 0, 0);
        }
    };

#define RDA(P, qm, fm, ks) (*(const bf16x8*)(smem + (P) * 24576 + (qm) * 4096 \
                             + ((arow + (fm) * 16) << 6) + coff[ks]))
#define RDB(P, g, ks)      (*(const bf16x8*)(smem + (P) * 24576 + 8192 + bsel \
                             + ((brow + (g) * 16) << 6) + coff[ks]))
#define MFMA16(MB, AH) do { \
    _Pragma("unroll") for (int fm_ = 0; fm_ < 2; ++fm_) \
    _Pragma("unroll") for (int g_ = 0; g_ < 4; ++g_) \
    _Pragma("unroll") for (int ks_ = 0; ks_ < 2; ++ks_) \
        acc[(MB) + fm_][g_] = __builtin_amdgcn_mfma_f32_16x16x32_bf16( \
            AH[fm_][ks_], b[g_][ks_], acc[(MB) + fm_][g_], 0, 0, 0); \
} while (0)

    // prologue: tile0 fully (6 loads) + tile1 {A0, B} (5 loads);
    // A1(tile1) is staged at ph1 of tile0. Oldest 6 must land -> vmcnt(5).
    stageA(0, 0, 0);  stageA(0, 1, 0);  stageB(0, 0, 0);  stageB(0, 1, 0);
    stageA(1, 0, 64); stageB(1, 0, 64); stageB(1, 1, 64);
    asm volatile("s_waitcnt vmcnt(5)" ::: "memory");
    BARRIER;

    bf16x8 a[2][2], b[4][2];

#define TILE2(JT, P) do { \
    const int kn_ = ((JT) + 2) * 64; \
    /* ---- ph1: stage A1(j+1); read a0 + all b; MFMA rows 0-1 ---- */ \
    if ((JT) + 1 < 16) stageA(1 - (P), 1, ((JT) + 1) * 64); \
    _Pragma("unroll") for (int fm_ = 0; fm_ < 2; ++fm_) \
    _Pragma("unroll") for (int ks_ = 0; ks_ < 2; ++ks_) a[fm_][ks_] = RDA(P, 0, fm_, ks_); \
    _Pragma("unroll") for (int g_ = 0; g_ < 4; ++g_) \
    _Pragma("unroll") for (int ks_ = 0; ks_ < 2; ++ks_) b[g_][ks_] = RDB(P, g_, ks_); \
    BARRIER; \
    __builtin_amdgcn_s_setprio(1); MFMA16(0, a); __builtin_amdgcn_s_setprio(0); \
    BARRIER; \
    /* ---- ph2: stage A0+B(j+2); read a1; MFMA rows 2-3 ---- */ \
    if ((JT) + 2 < 16) { stageA(P, 0, kn_); stageB(P, 0, kn_); stageB(P, 1, kn_); } \
    _Pragma("unroll") for (int fm_ = 0; fm_ < 2; ++fm_) \
    _Pragma("unroll") for (int ks_ = 0; ks_ < 2; ++ks_) a[fm_][ks_] = RDA(P, 1, fm_, ks_); \
    BARRIER; \
    __builtin_amdgcn_s_setprio(1); MFMA16(2, a); __builtin_amdgcn_s_setprio(0); \
    if ((JT) + 2 < 16)      { asm volatile("s_waitcnt vmcnt(5)" ::: "memory"); } \
    else if ((JT) + 1 < 16) { asm volatile("s_waitcnt vmcnt(0)" ::: "memory"); } \
    BARRIER; \
} while (0)

    for (int it = 0; it < 8; ++it) {
        TILE2(2 * it, 0);
        TILE2(2 * it + 1, 1);
    }
#undef TILE2
#undef RDA
#undef RDB
#undef MFMA16
}

// ---------------------------------------------------------------------------
// GEMM1 + fused RoPE + head-major scatter. Q pre-scaled by 0.125*log2e
// (applied on fp32 acc before the single bf16 rounding).
// ---------------------------------------------------------------------------
__global__ __launch_bounds__(512, 2)
void gemm_rope_kernel(const __bf16* __restrict__ A, const __bf16* __restrict__ BT,
                      __bf16* __restrict__ Qr, __bf16* __restrict__ Kr,
                      __bf16* __restrict__ Vt, const float* __restrict__ rt)
{
    extern __shared__ __align__(16) __bf16 smem[];
    const int id  = blockIdx.x;              // 768 = 64 m-tiles x 12 n-tiles
    const int xcd = id & 7, lid = id >> 3;   // bijective XCD swizzle (768%8==0)
    const int tm  = xcd * 8 + lid / 12;
    const int tn  = lid % 12;
    const int m0  = tm * 128, n0 = tn * 256;

    floatx4 acc[4][4] = {};
    gemm_pipe(A, BT, m0, n0, smem, acc);

    const int tid  = threadIdx.x;
    const int wave = tid >> 6;
    const int lane = tid & 63;
    const int quad = lane >> 4, l16 = lane & 15;
    const int wr   = wave >> 2, wc = wave & 3;

    const int gn0    = n0 + wc * 64;
    const int region = gn0 >> 10;             // 0=Q, 1=K, 2=V
    const int h      = (gn0 >> 6) & 15;

    if (region == 2) {
#pragma unroll
        for (int f = 0; f < 4; ++f) {
            const int gm = m0 + (f >> 1) * 64 + wr * 32 + (f & 1) * 16 + quad * 4;
            const int b = gm >> 11, s = gm & 2047;
#pragma unroll
            for (int g = 0; g < 4; ++g) {
                const int d = g * 16 + l16;
                bf16x4 w;
#pragma unroll
                for (int r = 0; r < 4; ++r) w[r] = (__bf16)acc[f][g][r];
                *(bf16x4*)(Vt + ((size_t)(b * 16 + h) * 64 + d) * 2048 + s) = w;
            }
        }
    } else {
        __bf16* dst = region ? Kr : Qr;
        const float sc = region ? 1.0f : SOFTMAX_SCALE_LOG2;   // pre-scale Q
#pragma unroll
        for (int g = 0; g < 2; ++g) {
            const int d1 = g * 16 + l16;
#pragma unroll
            for (int f = 0; f < 4; ++f) {
                const int gm0 = m0 + (f >> 1) * 64 + wr * 32 + (f & 1) * 16 + quad * 4;
                const int b = gm0 >> 11, s0 = gm0 & 2047;
#pragma unroll
                for (int r = 0; r < 4; ++r) {
                    const floatx2 t = *(const floatx2*)(rt + ((s0 + r) * 32 + d1) * 2);
                    const float a1 = acc[f][g][r];
                    const float a2 = acc[f][g + 2][r];
                    __bf16* row = dst + ((size_t)((b * 16 + h) * 2048 + s0 + r)) * 64;
                    row[d1]      = (__bf16)((a1 * t[0] - a2 * t[1]) * sc);
                    row[d1 + 32] = (__bf16)((a2 * t[0] + a1 * t[1]) * sc);
                }
            }
        }
    }
}

// ---------------------------------------------------------------------------
// GEMM2: out[8192][1024] = ctx * wob^T, pipelined core (same v2 core).
// ---------------------------------------------------------------------------
__global__ __launch_bounds__(512, 2)
void gemm_bt_kernel(const __bf16* __restrict__ A, const __bf16* __restrict__ BT,
                    float* __restrict__ C)
{
    extern __shared__ __align__(16) __bf16 smem[];
    const int id  = blockIdx.x;
    const int xcd = id & 7, lid = id >> 3;
    const int tm  = xcd * 8 + (lid >> 2);
    const int tn  = lid & 3;
    const int m0  = tm * 128, n0 = tn * 256;

    floatx4 acc[4][4] = {};
    gemm_pipe(A, BT, m0, n0, smem, acc);

    const int tid  = threadIdx.x;
    const int wave = tid >> 6, lane = tid & 63;
    const int quad = lane >> 4, l16 = lane & 15;
    const int wr   = wave >> 2, wc = wave & 3;

#pragma unroll
    for (int f = 0; f < 4; ++f) {
        const int row = m0 + (f >> 1) * 64 + wr * 32 + (f & 1) * 16 + quad * 4;
#pragma unroll
        for (int g = 0; g < 4; ++g) {
            const int col = n0 + wc * 64 + g * 16 + l16;
#pragma unroll
            for (int r = 0; r < 4; ++r)
                C[(size_t)(row + r) * 1024 + col] = acc[f][g][r];
        }
    }
}

// ---------------------------------------------------------------------------
// Causal flash attention v9 — R1 geometry + T14 async-STAGE split
// (unchanged from R4; attn dropped out of the top-5 with this version).
// ---------------------------------------------------------------------------
__global__ __launch_bounds__(256, 4)
void attn_kernel(const __bf16* __restrict__ Qr, const __bf16* __restrict__ Kr,
                 const __bf16* __restrict__ Vt, __bf16* __restrict__ ctx)
{
    __shared__ __align__(16) __bf16 Ks[64 * 64];        // [key][dh] swizzled
    __shared__ __align__(16) __bf16 Vs[64 * 64];        // [dh][key] swizzled
    __shared__ __align__(16) __bf16 plds[4][16 * 72];   // wave-private P staging

    const int bh   = blockIdx.x;
    const int b    = bh >> 4, h = bh & 15;
    const int tid  = threadIdx.x;
    const int wave = tid >> 6;
    const int lane = tid & 63;
    const int quad = lane >> 4, l16 = lane & 15;
    const int sw   = l16 & 7;                 // read-side XOR swizzle

    const __bf16* Qb = Qr + (size_t)bh * 2048 * 64;
    const __bf16* Kb = Kr + (size_t)bh * 2048 * 64;
    const __bf16* Vb = Vt + (size_t)bh * 64 * 2048;
    __bf16* Pw = &plds[wave][0];

    const int row0 = tid >> 3, jg0 = (tid & 7) ^ (row0 & 7);
    const int c1   = 256 + tid;
    const int row1 = c1 >> 3, jg1 = (c1 & 7) ^ (row1 & 7);

    const __bf16* pK0 = Kb + (size_t)row0 * 64 + jg0 * 8;
    const __bf16* pK1 = Kb + (size_t)row1 * 64 + jg1 * 8;
    const __bf16* pV0 = Vb + (size_t)row0 * 2048 + jg0 * 8;
    const __bf16* pV1 = Vb + (size_t)row1 * 2048 + jg1 * 8;

    const int tiles[2] = { (int)blockIdx.y, 31 - (int)blockIdx.y };

    for (int pass = 0; pass < 2; ++pass) {
        const int tq    = tiles[pass];
        const int q0    = tq * 64 + wave * 16;
        const int qa    = q0 + l16;
        const int ntile = tq + 1;

        bf16x8 bq[2];
#pragma unroll
        for (int t = 0; t < 2; ++t)
            bq[t] = *(const bf16x8*)(Qb + (q0 + l16) * 64 + t * 32 + quad * 8);

        floatx4 o[4] = {};
        float lpart = 0.f;

        // prologue: tile-0 K/V into registers
        bf16x8 rk0 = *(const bf16x8*)pK0;
        bf16x8 rk1 = *(const bf16x8*)pK1;
        bf16x8 rv0 = *(const bf16x8*)pV0;
        bf16x8 rv1 = *(const bf16x8*)pV1;

        __syncthreads();     // all waves done reading Ks/Vs of previous pass

        for (int t = 0; t < ntile; ++t) {
            // ---- write phase: regs (tile t) -> LDS
            asm volatile("s_waitcnt vmcnt(0)" ::: "memory");
            *(bf16x8*)(Ks + tid * 8)        = rk0;
            *(bf16x8*)(Ks + 2048 + tid * 8) = rk1;
            *(bf16x8*)(Vs + tid * 8)        = rv0;
            *(bf16x8*)(Vs + 2048 + tid * 8) = rv1;
            asm volatile("s_waitcnt lgkmcnt(0)" ::: "memory");
            BARRIER;

            // ---- issue next tile's loads (overlap with all compute below)
            if (t + 1 < ntile) {
                rk0 = *(const bf16x8*)(pK0 + (size_t)(t + 1) * 4096);
                rk1 = *(const bf16x8*)(pK1 + (size_t)(t + 1) * 4096);
                rv0 = *(const bf16x8*)(pV0 + (t + 1) * 64);
                rv1 = *(const bf16x8*)(pV1 + (t + 1) * 64);
            }

            const int  kt     = t * 64;
            const bool masked = (t == ntile - 1);   // only diag tile crosses q

            // ---- QK^T
            floatx4 s[4] = {};
            __builtin_amdgcn_s_setprio(1);
#pragma unroll
            for (int st = 0; st < 4; ++st) {
                bf16x8 ka0 = *(const bf16x8*)(Ks + (st * 16 + l16) * 64 + ((0 + quad) ^ sw) * 8);
                bf16x8 ka1 = *(const bf16x8*)(Ks + (st * 16 + l16) * 64 + ((4 + quad) ^ sw) * 8);
                s[st] = __builtin_amdgcn_mfma_f32_16x16x32_bf16(ka0, bq[0], s[st], 0, 0, 0);
                s[st] = __builtin_amdgcn_mfma_f32_16x16x32_bf16(ka1, bq[1], s[st], 0, 0, 0);
            }
            __builtin_amdgcn_s_setprio(0);

            // ---- softmax (Q pre-scaled; exp2 direct)
#pragma unroll
            for (int st = 0; st < 4; ++st) {
                bf16x4 w;
#pragma unroll
                for (int r = 0; r < 4; ++r) {
                    float v = s[st][r];
                    if (masked) {
                        const int key = kt + st * 16 + quad * 4 + r;
                        v = (key > qa) ? MASKV : v;
                    }
                    const float p = __builtin_amdgcn_exp2f(v);
                    lpart += p;
                    w[r] = (__bf16)p;
                }
                *(bf16x4*)(Pw + l16 * 72 + st * 16 + quad * 4) = w;
            }

            asm volatile("s_waitcnt lgkmcnt(0)" ::: "memory");
            bf16x8 ap0 = *(const bf16x8*)(Pw + l16 * 72 + quad * 8);
            bf16x8 ap1 = *(const bf16x8*)(Pw + l16 * 72 + 32 + quad * 8);

            // ---- PV
            __builtin_amdgcn_s_setprio(1);
#pragma unroll
            for (int nt = 0; nt < 4; ++nt) {
                bf16x8 bv0 = *(const bf16x8*)(Vs + (nt * 16 + l16) * 64 + ((0 + quad) ^ sw) * 8);
                bf16x8 bv1 = *(const bf16x8*)(Vs + (nt * 16 + l16) * 64 + ((4 + quad) ^ sw) * 8);
                o[nt] = __builtin_amdgcn_mfma_f32_16x16x32_bf16(ap0, bv0, o[nt], 0, 0, 0);
                o[nt] = __builtin_amdgcn_mfma_f32_16x16x32_bf16(ap1, bv1, o[nt], 0, 0, 0);
            }
            __builtin_amdgcn_s_setprio(0);

            BARRIER;          // all waves' reads of tile t done -> next write
        }

        float l = lpart;
        l += __shfl_xor(l, 16, 64);
        l += __shfl_xor(l, 32, 64);
        float lr[4];
#pragma unroll
        for (int r = 0; r < 4; ++r)
            lr[r] = __shfl(l, quad * 4 + r, 64);
#pragma unroll
        for (int nt = 0; nt < 4; ++nt)
#pragma unroll
            for (int r = 0; r < 4; ++r) {
                const int srow = q0 + quad * 4 + r;
                const float inv_l = 1.0f / fmaxf(lr[r], 1e-20f);
                ctx[((size_t)(b * 2048 + srow)) * 1024 + h * 64 + nt * 16 + l16] =
                    (__bf16)(o[nt][r] * inv_l);
            }
    }
}

// ---------------------------------------------------------------------------
// Workspace layout (88.5 MiB):
//   xb   [ 0M..16M)   qkvb [16M..22M)   wob [22M..24M)
//   Qr   [24M..40M)   Kr   [40M..56M)   Vt  [56M..72M)   ctx [72M..88M)
//   rt   [88M..88.5M) rope cos/sin table (2048 x 32 float2)
// ---------------------------------------------------------------------------
extern "C" void kernel_launch(void* const* d_in, const int* in_sizes, int n_in,
                              void* d_out, int out_size, void* d_ws, size_t ws_size,
                              hipStream_t stream)
{
    const float* x   = (const float*)d_in[0];   // [4,2048,1024] fp32
    const float* qkv = (const float*)d_in[1];   // [3072,1024]   fp32 (N x K)
    const float* wo  = (const float*)d_in[2];   // [1024,1024]   fp32 (N x K)
    float* out = (float*)d_out;                 // [8192,1024]   fp32

    char* ws = (char*)d_ws;
    const size_t MB = 1024 * 1024;
    __bf16* xb   = (__bf16*)(ws);
    __bf16* qkvb = (__bf16*)(ws + 16 * MB);
    __bf16* wob  = (__bf16*)(ws + 22 * MB);
    __bf16* Qr   = (__bf16*)(ws + 24 * MB);
    __bf16* Kr   = (__bf16*)(ws + 40 * MB);
    __bf16* Vt   = (__bf16*)(ws + 56 * MB);
    __bf16* ctx  = (__bf16*)(ws + 72 * MB);
    float*  rt   = (float*) (ws + 88 * MB);

    hipFuncSetAttribute((const void*)gemm_rope_kernel,
                        hipFuncAttributeMaxDynamicSharedMemorySize, 98304);
    hipFuncSetAttribute((const void*)gemm_bt_kernel,
                        hipFuncAttributeMaxDynamicSharedMemorySize, 98304);

    // 0) conversions + rope table in one launch
    cvt3_kernel<<<12352, 256, 0, stream>>>(x, qkv, wo, xb, qkvb, wob, rt);
    // 1) QKV projection, 2-phase/16-MFMA pipelined, fused table-RoPE
    gemm_rope_kernel<<<768, 512, 98304, stream>>>(xb, qkvb, Qr, Kr, Vt, rt);
    // 2) causal flash attention (T14 reg-staged) -> ctx (bf16)
    attn_kernel<<<dim3(64, 16), 256, 0, stream>>>(Qr, Kr, Vt, ctx);
    // 3) output projection, pipelined -> fp32 out
    gemm_bt_kernel<<<256, 512, 98304, stream>>>(ctx, wob, out);
}

// Round 6
// 216.025 us; speedup vs baseline: 1.1737x; 1.0423x over previous
//
#include <hip/hip_runtime.h>
#include <math.h>

typedef __bf16 bf16x8 __attribute__((ext_vector_type(8)));
typedef __bf16 bf16x4 __attribute__((ext_vector_type(4)));
typedef float  floatx4 __attribute__((ext_vector_type(4)));
typedef float  floatx2 __attribute__((ext_vector_type(2)));

#define AS1(p) ((__attribute__((address_space(1))) void*)(p))
#define AS3(p) ((__attribute__((address_space(3))) void*)(p))

#define MASKV (-1.0e30f)
#define SOFTMAX_SCALE_LOG2 0.1803368801111244f   // 0.125 * log2(e)
#define ROPE_LOG2F 0.4152410118609203f           // log2(10000)/32

// raw barrier (no vmcnt drain, unlike __syncthreads) + compile-time sched fence
#define BARRIER do { __builtin_amdgcn_sched_barrier(0); \
                     __builtin_amdgcn_s_barrier(); \
                     __builtin_amdgcn_sched_barrier(0); } while (0)

// ---------------------------------------------------------------------------
// One-shot fp32 -> bf16 conversion of x/qkv/wo + rope cos/sin table build.
// ---------------------------------------------------------------------------
__global__ __launch_bounds__(256)
void cvt3_kernel(const float* __restrict__ x, const float* __restrict__ qkv,
                 const float* __restrict__ wo, __bf16* __restrict__ xb,
                 __bf16* __restrict__ qkvb, __bf16* __restrict__ wob,
                 float* __restrict__ rt)
{
    const int bi = blockIdx.x;
    if (bi >= 12288) {
        const int e0 = (bi - 12288) * 1024 + threadIdx.x * 4;
#pragma unroll
        for (int j = 0; j < 4; ++j) {
            const int e = e0 + j;
            const int s = e >> 5, d = e & 31;
            const float f = exp2f(-(float)d * ROPE_LOG2F);
            float sn, cs;
            sincosf((float)s * f, &sn, &cs);
            floatx2 t; t[0] = cs; t[1] = sn;
            *(floatx2*)(rt + e * 2) = t;
        }
        return;
    }
    const float* src;
    __bf16* dst;
    int base;
    if (bi < 8192)       { src = x;   dst = xb;   base = bi * 1024; }
    else if (bi < 11264) { src = qkv; dst = qkvb; base = (bi - 8192) * 1024; }
    else                 { src = wo;  dst = wob;  base = (bi - 11264) * 1024; }

    const int i = base + threadIdx.x * 4;
    const floatx4 v = *(const floatx4*)(src + i);
    bf16x4 o;
    o[0] = (__bf16)v[0]; o[1] = (__bf16)v[1];
    o[2] = (__bf16)v[2]; o[3] = (__bf16)v[3];
    *(bf16x4*)(dst + i) = o;
}

// ---------------------------------------------------------------------------
// Pipelined 128x256 GEMM core v3 (C = A[128xK] * BT[256xK]^T tile), K=1024,
// BK=64, 8 waves (2M x 4N). TRIPLE-buffered LDS, ONE barrier + ONE counted
// vmcnt per K-tile; ds_reads, stage-issues and 32 MFMAs share one region so
// the compiler can run LDS reads UNDER MFMA execution (v2's 2-phase barrier
// pairs serialized read-cluster vs MFMA-cluster -> 45% ceiling, 28.6% meas).
// Per K-tile j (P=j%3, stage target T=(j+2)%3 = buffer last read at j-1):
//   [16 ds_read_b128 (a0,b,a1) || 6 global_load_lds into T || 32 MFMA]
//   vmcnt(6)   (waits tile j+1's 6 loads; j+2's 6 remain in flight)
//   BARRIER
// Race ledger: T last read at tile j-1, certified drained by tile j's entry
// barrier (reads are MFMA-consumed before each wave reaches it); stage(j+3)
// by a fast wave targets buf(j%3) only after tile j's end barrier. vmcnt is
// per-wave counted + barrier-joined -> all waves' loads visible. Never 0
// mid-loop. LDS: 3 bufs x 48 KB = 144 KB (1 block/CU, same as before).
// XOR swizzle byte^=(row&7)<<4, inverse-swizzled global source (rule 21).
// ---------------------------------------------------------------------------
__device__ __forceinline__ void gemm_pipe(const __bf16* __restrict__ Ap,
                                          const __bf16* __restrict__ Bp,
                                          const int m0, const int n0,
                                          __bf16* smem, floatx4 (&acc)[4][4])
{
    const int tid  = threadIdx.x;
    const int wave = tid >> 6;
    const int lane = tid & 63;
    const int quad = lane >> 4;
    const int l16  = lane & 15;
    const int wr   = wave >> 2;
    const int wc   = wave & 3;

    const int arow = wr * 32 + l16;
    const int brow = (wc & 1) * 64 + l16;
    const int bsel = (wc >> 1) * 8192;
    const int swz  = (l16 & 7) << 4;
    int coff[2];
    coff[0] = (( (quad << 4))        ^ swz) >> 1;
    coff[1] = ((64 | (quad << 4))    ^ swz) >> 1;

    auto stageA = [&](int buf, int h, int k0) {          // 1 load/thread (8KB)
        const int o = tid << 4;
        const int r = o >> 7;
        const int c = (o & 127) ^ ((r & 7) << 4);
        const __bf16* src = Ap + (size_t)(m0 + h * 64 + r) * 1024 + k0 + (c >> 1);
        __builtin_amdgcn_global_load_lds(AS1(src),
            AS3(smem + buf * 24576 + h * 4096 + wave * 512), 16, 0, 0);
    };
    auto stageB = [&](int buf, int h, int k0) {          // 2 loads/thread (16KB)
#pragma unroll
        for (int q = 0; q < 2; ++q) {
            const int o = (q * 512 + tid) << 4;
            const int r = o >> 7;
            const int c = (o & 127) ^ ((r & 7) << 4);
            const __bf16* src = Bp + (size_t)(n0 + h * 128 + r) * 1024 + k0 + (c >> 1);
            __builtin_amdgcn_global_load_lds(AS1(src),
                AS3(smem + buf * 24576 + 8192 + h * 8192 + (q * 8 + wave) * 512), 16, 0, 0);
        }
    };

#define RDA(P, qm, fm, ks) (*(const bf16x8*)(smem + (P) * 24576 + (qm) * 4096 \
                             + ((arow + (fm) * 16) << 6) + coff[ks]))
#define RDB(P, g, ks)      (*(const bf16x8*)(smem + (P) * 24576 + 8192 + bsel \
                             + ((brow + (g) * 16) << 6) + coff[ks]))
#define MFMA16(MB, AH) do { \
    _Pragma("unroll") for (int fm_ = 0; fm_ < 2; ++fm_) \
    _Pragma("unroll") for (int g_ = 0; g_ < 4; ++g_) \
    _Pragma("unroll") for (int ks_ = 0; ks_ < 2; ++ks_) \
        acc[(MB) + fm_][g_] = __builtin_amdgcn_mfma_f32_16x16x32_bf16( \
            AH[fm_][ks_], b[g_][ks_], acc[(MB) + fm_][g_], 0, 0, 0); \
} while (0)

    // prologue: full stage of tile0 (6 loads) + tile1 (6 loads);
    // wait tile0's 6 (12 outstanding -> vmcnt(6)).
    stageA(0, 0, 0);  stageA(0, 1, 0);  stageB(0, 0, 0);  stageB(0, 1, 0);
    stageA(1, 0, 64); stageA(1, 1, 64); stageB(1, 0, 64); stageB(1, 1, 64);
    asm volatile("s_waitcnt vmcnt(6)" ::: "memory");
    BARRIER;

    bf16x8 a0[2][2], a1[2][2], b[4][2];

#define TILE3(JT) do { \
    const int P_ = (JT) % 3, T_ = ((JT) + 2) % 3; \
    const int kn_ = ((JT) + 2) * 64; \
    _Pragma("unroll") for (int fm_ = 0; fm_ < 2; ++fm_) \
    _Pragma("unroll") for (int ks_ = 0; ks_ < 2; ++ks_) a0[fm_][ks_] = RDA(P_, 0, fm_, ks_); \
    _Pragma("unroll") for (int g_ = 0; g_ < 4; ++g_) \
    _Pragma("unroll") for (int ks_ = 0; ks_ < 2; ++ks_) b[g_][ks_] = RDB(P_, g_, ks_); \
    _Pragma("unroll") for (int fm_ = 0; fm_ < 2; ++fm_) \
    _Pragma("unroll") for (int ks_ = 0; ks_ < 2; ++ks_) a1[fm_][ks_] = RDA(P_, 1, fm_, ks_); \
    if ((JT) + 2 < 16) { stageA(T_, 0, kn_); stageA(T_, 1, kn_); \
                         stageB(T_, 0, kn_); stageB(T_, 1, kn_); } \
    __builtin_amdgcn_s_setprio(1); \
    MFMA16(0, a0); MFMA16(2, a1); \
    __builtin_amdgcn_s_setprio(0); \
    if ((JT) + 2 < 16)      { asm volatile("s_waitcnt vmcnt(6)" ::: "memory"); } \
    else if ((JT) + 1 < 16) { asm volatile("s_waitcnt vmcnt(0)" ::: "memory"); } \
    BARRIER; \
} while (0)

    TILE3(0);  TILE3(1);  TILE3(2);  TILE3(3);
    TILE3(4);  TILE3(5);  TILE3(6);  TILE3(7);
    TILE3(8);  TILE3(9);  TILE3(10); TILE3(11);
    TILE3(12); TILE3(13); TILE3(14); TILE3(15);

#undef TILE3
#undef RDA
#undef RDB
#undef MFMA16
}

// ---------------------------------------------------------------------------
// GEMM1 + fused RoPE + head-major scatter. Q pre-scaled by 0.125*log2e
// (applied on fp32 acc before the single bf16 rounding).
// ---------------------------------------------------------------------------
__global__ __launch_bounds__(512, 2)
void gemm_rope_kernel(const __bf16* __restrict__ A, const __bf16* __restrict__ BT,
                      __bf16* __restrict__ Qr, __bf16* __restrict__ Kr,
                      __bf16* __restrict__ Vt, const float* __restrict__ rt)
{
    extern __shared__ __align__(16) __bf16 smem[];
    const int id  = blockIdx.x;              // 768 = 64 m-tiles x 12 n-tiles
    const int xcd = id & 7, lid = id >> 3;   // bijective XCD swizzle (768%8==0)
    const int tm  = xcd * 8 + lid / 12;
    const int tn  = lid % 12;
    const int m0  = tm * 128, n0 = tn * 256;

    floatx4 acc[4][4] = {};
    gemm_pipe(A, BT, m0, n0, smem, acc);

    const int tid  = threadIdx.x;
    const int wave = tid >> 6;
    const int lane = tid & 63;
    const int quad = lane >> 4, l16 = lane & 15;
    const int wr   = wave >> 2, wc = wave & 3;

    const int gn0    = n0 + wc * 64;
    const int region = gn0 >> 10;             // 0=Q, 1=K, 2=V
    const int h      = (gn0 >> 6) & 15;

    if (region == 2) {
#pragma unroll
        for (int f = 0; f < 4; ++f) {
            const int gm = m0 + (f >> 1) * 64 + wr * 32 + (f & 1) * 16 + quad * 4;
            const int b = gm >> 11, s = gm & 2047;
#pragma unroll
            for (int g = 0; g < 4; ++g) {
                const int d = g * 16 + l16;
                bf16x4 w;
#pragma unroll
                for (int r = 0; r < 4; ++r) w[r] = (__bf16)acc[f][g][r];
                *(bf16x4*)(Vt + ((size_t)(b * 16 + h) * 64 + d) * 2048 + s) = w;
            }
        }
    } else {
        __bf16* dst = region ? Kr : Qr;
        const float sc = region ? 1.0f : SOFTMAX_SCALE_LOG2;   // pre-scale Q
#pragma unroll
        for (int g = 0; g < 2; ++g) {
            const int d1 = g * 16 + l16;
#pragma unroll
            for (int f = 0; f < 4; ++f) {
                const int gm0 = m0 + (f >> 1) * 64 + wr * 32 + (f & 1) * 16 + quad * 4;
                const int b = gm0 >> 11, s0 = gm0 & 2047;
#pragma unroll
                for (int r = 0; r < 4; ++r) {
                    const floatx2 t = *(const floatx2*)(rt + ((s0 + r) * 32 + d1) * 2);
                    const float a1 = acc[f][g][r];
                    const float a2 = acc[f][g + 2][r];
                    __bf16* row = dst + ((size_t)((b * 16 + h) * 2048 + s0 + r)) * 64;
                    row[d1]      = (__bf16)((a1 * t[0] - a2 * t[1]) * sc);
                    row[d1 + 32] = (__bf16)((a2 * t[0] + a1 * t[1]) * sc);
                }
            }
        }
    }
}

// ---------------------------------------------------------------------------
// GEMM2: out[8192][1024] = ctx * wob^T, pipelined core (same v3 core).
// ---------------------------------------------------------------------------
__global__ __launch_bounds__(512, 2)
void gemm_bt_kernel(const __bf16* __restrict__ A, const __bf16* __restrict__ BT,
                    float* __restrict__ C)
{
    extern __shared__ __align__(16) __bf16 smem[];
    const int id  = blockIdx.x;
    const int xcd = id & 7, lid = id >> 3;
    const int tm  = xcd * 8 + (lid >> 2);
    const int tn  = lid & 3;
    const int m0  = tm * 128, n0 = tn * 256;

    floatx4 acc[4][4] = {};
    gemm_pipe(A, BT, m0, n0, smem, acc);

    const int tid  = threadIdx.x;
    const int wave = tid >> 6, lane = tid & 63;
    const int quad = lane >> 4, l16 = lane & 15;
    const int wr   = wave >> 2, wc = wave & 3;

#pragma unroll
    for (int f = 0; f < 4; ++f) {
        const int row = m0 + (f >> 1) * 64 + wr * 32 + (f & 1) * 16 + quad * 4;
#pragma unroll
        for (int g = 0; g < 4; ++g) {
            const int col = n0 + wc * 64 + g * 16 + l16;
#pragma unroll
            for (int r = 0; r < 4; ++r)
                C[(size_t)(row + r) * 1024 + col] = acc[f][g][r];
        }
    }
}

// ---------------------------------------------------------------------------
// Causal flash attention v9 — R1 geometry + T14 async-STAGE split
// (unchanged from R4; attn dropped out of the top-5 with this version).
// ---------------------------------------------------------------------------
__global__ __launch_bounds__(256, 4)
void attn_kernel(const __bf16* __restrict__ Qr, const __bf16* __restrict__ Kr,
                 const __bf16* __restrict__ Vt, __bf16* __restrict__ ctx)
{
    __shared__ __align__(16) __bf16 Ks[64 * 64];        // [key][dh] swizzled
    __shared__ __align__(16) __bf16 Vs[64 * 64];        // [dh][key] swizzled
    __shared__ __align__(16) __bf16 plds[4][16 * 72];   // wave-private P staging

    const int bh   = blockIdx.x;
    const int b    = bh >> 4, h = bh & 15;
    const int tid  = threadIdx.x;
    const int wave = tid >> 6;
    const int lane = tid & 63;
    const int quad = lane >> 4, l16 = lane & 15;
    const int sw   = l16 & 7;                 // read-side XOR swizzle

    const __bf16* Qb = Qr + (size_t)bh * 2048 * 64;
    const __bf16* Kb = Kr + (size_t)bh * 2048 * 64;
    const __bf16* Vb = Vt + (size_t)bh * 64 * 2048;
    __bf16* Pw = &plds[wave][0];

    const int row0 = tid >> 3, jg0 = (tid & 7) ^ (row0 & 7);
    const int c1   = 256 + tid;
    const int row1 = c1 >> 3, jg1 = (c1 & 7) ^ (row1 & 7);

    const __bf16* pK0 = Kb + (size_t)row0 * 64 + jg0 * 8;
    const __bf16* pK1 = Kb + (size_t)row1 * 64 + jg1 * 8;
    const __bf16* pV0 = Vb + (size_t)row0 * 2048 + jg0 * 8;
    const __bf16* pV1 = Vb + (size_t)row1 * 2048 + jg1 * 8;

    const int tiles[2] = { (int)blockIdx.y, 31 - (int)blockIdx.y };

    for (int pass = 0; pass < 2; ++pass) {
        const int tq    = tiles[pass];
        const int q0    = tq * 64 + wave * 16;
        const int qa    = q0 + l16;
        const int ntile = tq + 1;

        bf16x8 bq[2];
#pragma unroll
        for (int t = 0; t < 2; ++t)
            bq[t] = *(const bf16x8*)(Qb + (q0 + l16) * 64 + t * 32 + quad * 8);

        floatx4 o[4] = {};
        float lpart = 0.f;

        // prologue: tile-0 K/V into registers
        bf16x8 rk0 = *(const bf16x8*)pK0;
        bf16x8 rk1 = *(const bf16x8*)pK1;
        bf16x8 rv0 = *(const bf16x8*)pV0;
        bf16x8 rv1 = *(const bf16x8*)pV1;

        __syncthreads();     // all waves done reading Ks/Vs of previous pass

        for (int t = 0; t < ntile; ++t) {
            // ---- write phase: regs (tile t) -> LDS
            asm volatile("s_waitcnt vmcnt(0)" ::: "memory");
            *(bf16x8*)(Ks + tid * 8)        = rk0;
            *(bf16x8*)(Ks + 2048 + tid * 8) = rk1;
            *(bf16x8*)(Vs + tid * 8)        = rv0;
            *(bf16x8*)(Vs + 2048 + tid * 8) = rv1;
            asm volatile("s_waitcnt lgkmcnt(0)" ::: "memory");
            BARRIER;

            // ---- issue next tile's loads (overlap with all compute below)
            if (t + 1 < ntile) {
                rk0 = *(const bf16x8*)(pK0 + (size_t)(t + 1) * 4096);
                rk1 = *(const bf16x8*)(pK1 + (size_t)(t + 1) * 4096);
                rv0 = *(const bf16x8*)(pV0 + (t + 1) * 64);
                rv1 = *(const bf16x8*)(pV1 + (t + 1) * 64);
            }

            const int  kt     = t * 64;
            const bool masked = (t == ntile - 1);   // only diag tile crosses q

            // ---- QK^T
            floatx4 s[4] = {};
            __builtin_amdgcn_s_setprio(1);
#pragma unroll
            for (int st = 0; st < 4; ++st) {
                bf16x8 ka0 = *(const bf16x8*)(Ks + (st * 16 + l16) * 64 + ((0 + quad) ^ sw) * 8);
                bf16x8 ka1 = *(const bf16x8*)(Ks + (st * 16 + l16) * 64 + ((4 + quad) ^ sw) * 8);
                s[st] = __builtin_amdgcn_mfma_f32_16x16x32_bf16(ka0, bq[0], s[st], 0, 0, 0);
                s[st] = __builtin_amdgcn_mfma_f32_16x16x32_bf16(ka1, bq[1], s[st], 0, 0, 0);
            }
            __builtin_amdgcn_s_setprio(0);

            // ---- softmax (Q pre-scaled; exp2 direct)
#pragma unroll
            for (int st = 0; st < 4; ++st) {
                bf16x4 w;
#pragma unroll
                for (int r = 0; r < 4; ++r) {
                    float v = s[st][r];
                    if (masked) {
                        const int key = kt + st * 16 + quad * 4 + r;
                        v = (key > qa) ? MASKV : v;
                    }
                    const float p = __builtin_amdgcn_exp2f(v);
                    lpart += p;
                    w[r] = (__bf16)p;
                }
                *(bf16x4*)(Pw + l16 * 72 + st * 16 + quad * 4) = w;
            }

            asm volatile("s_waitcnt lgkmcnt(0)" ::: "memory");
            bf16x8 ap0 = *(const bf16x8*)(Pw + l16 * 72 + quad * 8);
            bf16x8 ap1 = *(const bf16x8*)(Pw + l16 * 72 + 32 + quad * 8);

            // ---- PV
            __builtin_amdgcn_s_setprio(1);
#pragma unroll
            for (int nt = 0; nt < 4; ++nt) {
                bf16x8 bv0 = *(const bf16x8*)(Vs + (nt * 16 + l16) * 64 + ((0 + quad) ^ sw) * 8);
                bf16x8 bv1 = *(const bf16x8*)(Vs + (nt * 16 + l16) * 64 + ((4 + quad) ^ sw) * 8);
                o[nt] = __builtin_amdgcn_mfma_f32_16x16x32_bf16(ap0, bv0, o[nt], 0, 0, 0);
                o[nt] = __builtin_amdgcn_mfma_f32_16x16x32_bf16(ap1, bv1, o[nt], 0, 0, 0);
            }
            __builtin_amdgcn_s_setprio(0);

            BARRIER;          // all waves' reads of tile t done -> next write
        }

        float l = lpart;
        l += __shfl_xor(l, 16, 64);
        l += __shfl_xor(l, 32, 64);
        float lr[4];
#pragma unroll
        for (int r = 0; r < 4; ++r)
            lr[r] = __shfl(l, quad * 4 + r, 64);
#pragma unroll
        for (int nt = 0; nt < 4; ++nt)
#pragma unroll
            for (int r = 0; r < 4; ++r) {
                const int srow = q0 + quad * 4 + r;
                const float inv_l = 1.0f / fmaxf(lr[r], 1e-20f);
                ctx[((size_t)(b * 2048 + srow)) * 1024 + h * 64 + nt * 16 + l16] =
                    (__bf16)(o[nt][r] * inv_l);
            }
    }
}

// ---------------------------------------------------------------------------
// Workspace layout (88.5 MiB):
//   xb   [ 0M..16M)   qkvb [16M..22M)   wob [22M..24M)
//   Qr   [24M..40M)   Kr   [40M..56M)   Vt  [56M..72M)   ctx [72M..88M)
//   rt   [88M..88.5M) rope cos/sin table (2048 x 32 float2)
// ---------------------------------------------------------------------------
extern "C" void kernel_launch(void* const* d_in, const int* in_sizes, int n_in,
                              void* d_out, int out_size, void* d_ws, size_t ws_size,
                              hipStream_t stream)
{
    const float* x   = (const float*)d_in[0];   // [4,2048,1024] fp32
    const float* qkv = (const float*)d_in[1];   // [3072,1024]   fp32 (N x K)
    const float* wo  = (const float*)d_in[2];   // [1024,1024]   fp32 (N x K)
    float* out = (float*)d_out;                 // [8192,1024]   fp32

    char* ws = (char*)d_ws;
    const size_t MB = 1024 * 1024;
    __bf16* xb   = (__bf16*)(ws);
    __bf16* qkvb = (__bf16*)(ws + 16 * MB);
    __bf16* wob  = (__bf16*)(ws + 22 * MB);
    __bf16* Qr   = (__bf16*)(ws + 24 * MB);
    __bf16* Kr   = (__bf16*)(ws + 40 * MB);
    __bf16* Vt   = (__bf16*)(ws + 56 * MB);
    __bf16* ctx  = (__bf16*)(ws + 72 * MB);
    float*  rt   = (float*) (ws + 88 * MB);

    // 144 KiB dynamic LDS (3 buffers) for the pipelined GEMMs
    hipFuncSetAttribute((const void*)gemm_rope_kernel,
                        hipFuncAttributeMaxDynamicSharedMemorySize, 147456);
    hipFuncSetAttribute((const void*)gemm_bt_kernel,
                        hipFuncAttributeMaxDynamicSharedMemorySize, 147456);

    // 0) conversions + rope table in one launch
    cvt3_kernel<<<12352, 256, 0, stream>>>(x, qkv, wo, xb, qkvb, wob, rt);
    // 1) QKV projection, 3-buffer/1-barrier pipelined, fused table-RoPE
    gemm_rope_kernel<<<768, 512, 147456, stream>>>(xb, qkvb, Qr, Kr, Vt, rt);
    // 2) causal flash attention (T14 reg-staged) -> ctx (bf16)
    attn_kernel<<<dim3(64, 16), 256, 0, stream>>>(Qr, Kr, Vt, ctx);
    // 3) output projection, pipelined -> fp32 out
    gemm_bt_kernel<<<256, 512, 147456, stream>>>(ctx, wob, out);
}